// Round 3
// baseline (1841.107 us; speedup 1.0000x reference)
//
#include <hip/hip_runtime.h>
#include <math.h>

// TriDirectionalMamba: C=64, N=16, DI=128, K=4, DT_RANK=4, L=48, 48^3 grid, B=1.
// Pipeline: prep (weight transposes) -> per dir: K1 (LN+in_proj token-parallel)
// -> K2 (conv+x_proj+scan per-seq) -> K3 (gate+out_proj+weighted accumulate).
// Workspace: tb[110592][256] fp32 (xin/res, z overwrites xin) = 113.2 MB,
// + transposed weights. Fallback to monolithic v1 kernel if ws too small.

#define CS   110592      // channel stride in x = 48*48*48
#define L2E  1.44269504088896340736f

#define IPT_OFF  (110592 * 256)            // floats
#define OPT_OFF  (IPT_OFF + 3 * 64 * 256)
#define WS_FLOATS (OPT_OFF + 3 * 128 * 64)

__device__ __forceinline__ float fast_silu(float x) {
    return x / (1.0f + __expf(-x));
}

// ---------------------------------------------------------------- prep ----
__global__ void prep_kernel(const float* __restrict__ ip,
                            const float* __restrict__ op,
                            float* __restrict__ ws)
{
    float* ipT = ws + IPT_OFF;
    float* opT = ws + OPT_OFF;
    int i = blockIdx.x * 256 + threadIdx.x;
    if (i < 3 * 256 * 64) {
        int dir = i / 16384, r = i % 16384, j = r / 64, c = r % 64;
        ipT[dir * 16384 + c * 256 + j] = ip[i];
    } else {
        int k = i - 3 * 256 * 64;
        if (k < 3 * 64 * 128) {
            int dir = k / 8192, r = k % 8192, c = r / 128, dch = r % 128;
            opT[dir * 8192 + dch * 64 + c] = op[k];
        }
    }
}

// ----------------------------------------------------------------- K1 -----
// One thread = one token. x-row staged in LDS (thread-private column) so it
// is runtime-indexable; weights stream via wave-uniform s_loads.
template<int DIR>
__global__ __launch_bounds__(256, 4)
void k1_lnproj(const float* __restrict__ x,
               const float* __restrict__ ln_g,
               const float* __restrict__ ln_b,
               float* __restrict__ ws)
{
    __shared__ float xl[64 * 256];
    const float* ipT = ws + IPT_OFF + DIR * 16384;
    float* tb = ws;
    const int tid = threadIdx.x;
    const int p = blockIdx.x * 256 + tid;
    const int d_sp = p / 2304;
    const int r = p - d_sp * 2304;
    const int h = r / 48;
    const int w = r - h * 48;
    int tau;
    if (DIR == 0)      tau = r * 48 + d_sp;
    else if (DIR == 1) tau = (d_sp * 48 + w) * 48 + h;
    else               tau = (d_sp * 48 + h) * 48 + w;

    float s1 = 0.f, s2 = 0.f;
    for (int c = 0; c < 64; c++) {
        float v = x[c * CS + p];
        xl[c * 256 + tid] = v;
        s1 += v; s2 += v * v;
    }
    float m  = s1 * (1.f / 64.f);
    float rs = rsqrtf(s2 * (1.f / 64.f) - m * m + 1e-5f);
    for (int c = 0; c < 64; c++) {
        xl[c * 256 + tid] = (xl[c * 256 + tid] - m) * rs * ln_g[DIR * 64 + c]
                            + ln_b[DIR * 64 + c];
    }

    float* dst = tb + tau * 256;
    for (int jc = 0; jc < 8; jc++) {
        float acc[32];
#pragma unroll
        for (int k = 0; k < 32; k++) acc[k] = 0.f;
#pragma unroll 2
        for (int c = 0; c < 64; c++) {
            float xv = xl[c * 256 + tid];
            const float4* wr = (const float4*)(ipT + c * 256 + jc * 32);
#pragma unroll
            for (int q = 0; q < 8; q++) {
                float4 w4 = wr[q];
                acc[4*q+0] += xv * w4.x; acc[4*q+1] += xv * w4.y;
                acc[4*q+2] += xv * w4.z; acc[4*q+3] += xv * w4.w;
            }
        }
        if (jc >= 4) {   // res half: store silu(res)
#pragma unroll
            for (int k = 0; k < 32; k++) acc[k] = fast_silu(acc[k]);
        }
#pragma unroll
        for (int q = 0; q < 8; q++) {
            float4 o; o.x = acc[4*q]; o.y = acc[4*q+1]; o.z = acc[4*q+2]; o.w = acc[4*q+3];
            ((float4*)(dst + jc * 32))[q] = o;
        }
    }
}

// ----------------------------------------------------------------- K2 -----
// One block = one sequence (128 thr). conv+silu (regs) -> x_proj -> scan.
// z written UNGATED (y + u*D); gating deferred to K3.
template<int DIR>
__global__ __launch_bounds__(128, 2)
void k2_scan(const float* __restrict__ conv_w,
             const float* __restrict__ conv_b,
             const float* __restrict__ x_proj,
             const float* __restrict__ dt_w,
             const float* __restrict__ dt_b,
             const float* __restrict__ A_log,
             const float* __restrict__ D_ssm,
             float* __restrict__ ws)
{
    __shared__ float u_s[48 * 132];   // rows 528B: 16B-aligned, conflict-free
    __shared__ float xd_s[48 * 40];   // [0:4]=dlt [4:20]=B [20:36]=C
    float* tb = ws;
    const int tid = threadIdx.x;
    const int t0 = blockIdx.x * 48 * 256;

    // --- phase A: depthwise causal conv + silu (thread = d) ---
    {
        const int d = tid;
        float xin[48];
#pragma unroll
        for (int t = 0; t < 48; t++) xin[t] = tb[t0 + t * 256 + d];
        float4 cw = *(const float4*)(conv_w + DIR * 512 + d * 4);
        float cb = conv_b[DIR * 128 + d];
#pragma unroll
        for (int t = 0; t < 48; t++) {
            float a0 = (t >= 3) ? xin[t-3] : 0.f;
            float a1 = (t >= 2) ? xin[t-2] : 0.f;
            float a2 = (t >= 1) ? xin[t-1] : 0.f;
            float v = cw.x * a0 + cw.y * a1 + cw.z * a2 + cw.w * xin[t] + cb;
            u_s[t * 132 + d] = fast_silu(v);
        }
    }
    __syncthreads();

    // --- phase B: x_proj u(128) -> x_dbl(36) (lane = t, j split by wave) ---
    {
        const int t = tid & 63;
        const int wv = __builtin_amdgcn_readfirstlane(tid >> 6);
        if (t < 48) {
            float ur[128];
            const float4* urow = (const float4*)&u_s[t * 132];
#pragma unroll
            for (int q = 0; q < 32; q++) {
                float4 v = urow[q];
                ur[4*q] = v.x; ur[4*q+1] = v.y; ur[4*q+2] = v.z; ur[4*q+3] = v.w;
            }
            for (int jj = 0; jj < 18; jj++) {
                int j = wv * 18 + jj;
                const float4* wr = (const float4*)(x_proj + DIR * 36 * 128 + j * 128);
                float a0 = 0.f, a1 = 0.f, a2 = 0.f, a3 = 0.f;
#pragma unroll
                for (int q = 0; q < 32; q++) {
                    float4 w4 = wr[q];
                    a0 += ur[4*q]   * w4.x; a1 += ur[4*q+1] * w4.y;
                    a2 += ur[4*q+2] * w4.z; a3 += ur[4*q+3] * w4.w;
                }
                xd_s[t * 40 + j] = (a0 + a1) + (a2 + a3);
            }
        }
    }
    __syncthreads();

    // --- phase C: selective scan (thread = d) ---
    {
        const int d = tid;
        float A2[16]; bool powok = true;
#pragma unroll
        for (int n = 0; n < 16; n++) {
            float a = -__expf(A_log[DIR * 2048 + d * 16 + n]);
            powok = powok && (fabsf(a + (float)(n + 1)) < 1e-3f);
            A2[n] = a * L2E;
        }
        float4 dtw = *(const float4*)(dt_w + DIR * 512 + d * 4);
        float dtbv = dt_b[DIR * 128 + d];
        float dsv  = D_ssm[DIR * 128 + d];
        float h[16];
#pragma unroll
        for (int n = 0; n < 16; n++) h[n] = 0.f;

        auto comp = [&](const float4* R, float uu, int tt) {
            float dl = dtbv + dtw.x*R[0].x + dtw.y*R[0].y + dtw.z*R[0].z + dtw.w*R[0].w;
            float delta = (dl > 20.f) ? dl : log1pf(__expf(dl));
            float du = delta * uu;
            float p = exp2f(-delta * L2E);
            float e[16]; e[0] = p;
#pragma unroll
            for (int n = 1; n < 16; n++) e[n] = e[n-1] * p;
            float Bf[16] = {R[1].x,R[1].y,R[1].z,R[1].w, R[2].x,R[2].y,R[2].z,R[2].w,
                            R[3].x,R[3].y,R[3].z,R[3].w, R[4].x,R[4].y,R[4].z,R[4].w};
            float Cf[16] = {R[5].x,R[5].y,R[5].z,R[5].w, R[6].x,R[6].y,R[6].z,R[6].w,
                            R[7].x,R[7].y,R[7].z,R[7].w, R[8].x,R[8].y,R[8].z,R[8].w};
            float y = 0.f;
#pragma unroll
            for (int n = 0; n < 16; n++) {
                h[n] = e[n] * h[n] + du * Bf[n];
                y += h[n] * Cf[n];
            }
            tb[t0 + tt * 256 + d] = y + uu * dsv;   // ungated
        };
        auto ldrow = [&](float4* R, int tt) {
            const float4* xr4 = (const float4*)&xd_s[tt * 40];
#pragma unroll
            for (int q = 0; q < 9; q++) R[q] = xr4[q];
        };

        if (powok) {
            float4 rA[9], rB[9]; float uA, uB;
            ldrow(rA, 0); uA = u_s[0 * 132 + d];
            ldrow(rB, 1); uB = u_s[1 * 132 + d];
            for (int k = 0; k < 24; k++) {
                int tt = 2 * k;
                comp(rA, uA, tt);
                if (k < 23) { ldrow(rA, tt + 2); uA = u_s[(tt + 2) * 132 + d]; }
                comp(rB, uB, tt + 1);
                if (k < 23) { ldrow(rB, tt + 3); uB = u_s[(tt + 3) * 132 + d]; }
            }
        } else {
            for (int tt = 0; tt < 48; tt++) {
                const float* xr = &xd_s[tt * 40];
                float4 dl4 = *(const float4*)xr;
                float dl = dtbv + dtw.x*dl4.x + dtw.y*dl4.y + dtw.z*dl4.z + dtw.w*dl4.w;
                float delta = (dl > 20.f) ? dl : log1pf(__expf(dl));
                float uu = u_s[tt * 132 + d];
                float du = delta * uu;
                float e[16];
#pragma unroll
                for (int n = 0; n < 16; n++) e[n] = exp2f(delta * A2[n]);
                float4 Bv0 = *(const float4*)(xr + 4);
                float4 Bv1 = *(const float4*)(xr + 8);
                float4 Bv2 = *(const float4*)(xr + 12);
                float4 Bv3 = *(const float4*)(xr + 16);
                float4 Cv0 = *(const float4*)(xr + 20);
                float4 Cv1 = *(const float4*)(xr + 24);
                float4 Cv2 = *(const float4*)(xr + 28);
                float4 Cv3 = *(const float4*)(xr + 32);
                float Bf[16] = {Bv0.x,Bv0.y,Bv0.z,Bv0.w, Bv1.x,Bv1.y,Bv1.z,Bv1.w,
                                Bv2.x,Bv2.y,Bv2.z,Bv2.w, Bv3.x,Bv3.y,Bv3.z,Bv3.w};
                float Cf[16] = {Cv0.x,Cv0.y,Cv0.z,Cv0.w, Cv1.x,Cv1.y,Cv1.z,Cv1.w,
                                Cv2.x,Cv2.y,Cv2.z,Cv2.w, Cv3.x,Cv3.y,Cv3.z,Cv3.w};
                float y = 0.f;
#pragma unroll
                for (int n = 0; n < 16; n++) {
                    h[n] = e[n] * h[n] + du * Bf[n];
                    y += h[n] * Cf[n];
                }
                tb[t0 + tt * 256 + d] = y + uu * dsv;
            }
        }
    }
}

// ----------------------------------------------------------------- K3 -----
// One block = one (d_sp, h) output row-pair: gates z*silu(res) while staging,
// out_proj via transposed weights, LDS transpose -> coalesced RMW into out.
template<int DIR, bool FIRST>
__global__ __launch_bounds__(128, 4)
void k3_outproj(const float* __restrict__ alpha,
                float* __restrict__ ws,
                float* __restrict__ out)
{
    __shared__ float sb[48 * 132];   // zt[48][132]; reused as outT[64][49]
    float* tb = ws;
    const float* opT = ws + OPT_OFF + DIR * 8192;
    const int tid = threadIdx.x;
    const int b = blockIdx.x;
    const int d_sp = b / 48;
    const int h = b - d_sp * 48;

    float a0 = alpha[0], a1 = alpha[1], a2 = alpha[2];
    float mx = fmaxf(a0, fmaxf(a1, a2));
    float e0 = __expf(a0 - mx), e1 = __expf(a1 - mx), e2 = __expf(a2 - mx);
    float wdir = ((DIR == 0) ? e0 : (DIR == 1) ? e1 : e2) / (e0 + e1 + e2);

#pragma unroll 4
    for (int w = 0; w < 48; w++) {
        int tau;
        if (DIR == 0)      tau = (h * 48 + w) * 48 + d_sp;
        else if (DIR == 1) tau = (d_sp * 48 + w) * 48 + h;
        else               tau = (d_sp * 48 + h) * 48 + w;
        float zv = tb[tau * 256 + tid];
        float rv = tb[tau * 256 + 128 + tid];
        sb[w * 132 + tid] = zv * rv;   // gate: z * silu(res)
    }
    __syncthreads();

    const int cp = tid & 31;
    const int wg = tid >> 5;
    float acc0[12], acc1[12];
#pragma unroll
    for (int i = 0; i < 12; i++) { acc0[i] = 0.f; acc1[i] = 0.f; }
#pragma unroll 2
    for (int dc = 0; dc < 32; dc++) {
        float w0[4], w1[4];
#pragma unroll
        for (int i = 0; i < 4; i++) {
            w0[i] = opT[(dc * 4 + i) * 64 + cp];
            w1[i] = opT[(dc * 4 + i) * 64 + cp + 32];
        }
#pragma unroll
        for (int i = 0; i < 12; i++) {
            int w = wg * 12 + i;
            float4 z4 = *(const float4*)&sb[w * 132 + dc * 4];
            acc0[i] += z4.x * w0[0] + z4.y * w0[1] + z4.z * w0[2] + z4.w * w0[3];
            acc1[i] += z4.x * w1[0] + z4.y * w1[1] + z4.z * w1[2] + z4.w * w1[3];
        }
    }
    __syncthreads();
#pragma unroll
    for (int i = 0; i < 12; i++) {
        int w = wg * 12 + i;
        sb[cp * 49 + w]        = acc0[i];
        sb[(cp + 32) * 49 + w] = acc1[i];
    }
    __syncthreads();
    const int obase = d_sp * 2304 + h * 48;
    for (int o = tid; o < 3072; o += 128) {
        int c = o / 48, w = o - c * 48;
        int addr = c * CS + obase + w;
        float val = wdir * sb[c * 49 + w];
        if (!FIRST) val += out[addr];
        out[addr] = val;
    }
}

// =================== fallback v1 (round-1, known-good) =====================
template<int DIR, bool FIRST>
__global__ __launch_bounds__(128, 2)
void mamba_dir_v1(const float* __restrict__ x, const float* __restrict__ in_proj,
                  const float* __restrict__ conv_w, const float* __restrict__ conv_b,
                  const float* __restrict__ x_proj, const float* __restrict__ dt_w,
                  const float* __restrict__ dt_b, const float* __restrict__ A_log,
                  const float* __restrict__ D_ssm, const float* __restrict__ out_proj,
                  const float* __restrict__ ln_g, const float* __restrict__ ln_b,
                  const float* __restrict__ alpha, float* __restrict__ out)
{
    __shared__ float xs_s[48 * 68];
    __shared__ float u_s[48 * 128];
    __shared__ float xd_s[48 * 40];
    const int tid = threadIdx.x;
    const int lane = tid & 63;
    const int wv = __builtin_amdgcn_readfirstlane(tid >> 6);
    const int s = blockIdx.x;
    int base, TS;
    if (DIR == 0)      { base = s;                               TS = 2304; }
    else if (DIR == 1) { base = (s / 48) * 2304 + (s % 48);      TS = 48;   }
    else               { base = (s / 48) * 2304 + (s % 48) * 48; TS = 1;    }
    const float* ip = in_proj + DIR * 256 * 64;
    const float* xp = x_proj + DIR * 36 * 128;
    const float* op = out_proj + DIR * 64 * 128;
    float a0 = alpha[0], a1 = alpha[1], a2 = alpha[2];
    float mx = fmaxf(a0, fmaxf(a1, a2));
    float e0 = __expf(a0 - mx), e1 = __expf(a1 - mx), e2 = __expf(a2 - mx);
    float wdir = ((DIR == 0) ? e0 : (DIR == 1) ? e1 : e2) / (e0 + e1 + e2);
    for (int o = tid; o < 48 * 64; o += 128) {
        int t = o % 48, c = o / 48;
        xs_s[t * 68 + c] = x[c * CS + base + t * TS];
    }
    __syncthreads();
    const int t = lane;
    float xr[64];
    if (t < 48) {
        const float4* row = (const float4*)&xs_s[t * 68];
#pragma unroll
        for (int q = 0; q < 16; q++) {
            float4 v = row[q];
            xr[4*q+0]=v.x; xr[4*q+1]=v.y; xr[4*q+2]=v.z; xr[4*q+3]=v.w;
        }
        float m = 0.f;
#pragma unroll
        for (int c = 0; c < 64; c++) m += xr[c];
        m *= (1.0f / 64.0f);
        float var = 0.f;
#pragma unroll
        for (int c = 0; c < 64; c++) { float d0 = xr[c] - m; var += d0 * d0; }
        var *= (1.0f / 64.0f);
        float rs = rsqrtf(var + 1e-5f);
#pragma unroll
        for (int c = 0; c < 64; c++)
            xr[c] = (xr[c] - m) * rs * ln_g[DIR * 64 + c] + ln_b[DIR * 64 + c];
    }
    __syncthreads();
    if (t < 48 && wv == 0) {
        float4* row = (float4*)&xs_s[t * 68];
#pragma unroll
        for (int q = 0; q < 16; q++) {
            float4 v; v.x=xr[4*q+0]; v.y=xr[4*q+1]; v.z=xr[4*q+2]; v.w=xr[4*q+3];
            row[q] = v;
        }
    }
    if (t < 48) {
        for (int jj = 0; jj < 64; jj++) {
            int j = wv * 64 + jj;
            const float4* wrow = (const float4*)(ip + j * 64);
            float acc = 0.f;
#pragma unroll
            for (int q = 0; q < 16; q++) {
                float4 w4 = wrow[q];
                acc += xr[4*q+0]*w4.x + xr[4*q+1]*w4.y + xr[4*q+2]*w4.z + xr[4*q+3]*w4.w;
            }
            int col = (((j >> 2) ^ (t & 7)) << 2) | (j & 3);
            u_s[t * 128 + col] = acc;
        }
    }
    __syncthreads();
    {
        const int d = tid;
        float4 cw = *(const float4*)(conv_w + DIR * 512 + d * 4);
        float cb = conv_b[DIR * 128 + d];
        float w0 = 0.f, w1 = 0.f, w2 = 0.f;
        for (int tt = 0; tt < 48; tt++) {
            int col = tt * 128 + ((((d >> 2) ^ (tt & 7)) << 2) | (d & 3));
            float w3 = u_s[col];
            float xc = cw.x*w0 + cw.y*w1 + cw.z*w2 + cw.w*w3 + cb;
            u_s[col] = fast_silu(xc);
            w0 = w1; w1 = w2; w2 = w3;
        }
    }
    __syncthreads();
    if (t < 48) {
        float ur[128];
        const float4* urow = (const float4*)&u_s[t * 128];
#pragma unroll
        for (int g = 0; g < 32; g++) {
            float4 v = urow[g ^ (t & 7)];
            ur[4*g]=v.x; ur[4*g+1]=v.y; ur[4*g+2]=v.z; ur[4*g+3]=v.w;
        }
        for (int jj = 0; jj < 18; jj++) {
            int j = wv * 18 + jj;
            const float4* wrow = (const float4*)(xp + j * 128);
            float acc = 0.f;
#pragma unroll
            for (int q = 0; q < 32; q++) {
                float4 w4 = wrow[q];
                acc += ur[4*q]*w4.x + ur[4*q+1]*w4.y + ur[4*q+2]*w4.z + ur[4*q+3]*w4.w;
            }
            xd_s[t * 40 + j] = acc;
        }
    }
    __syncthreads();
    {
        const int d = tid;
        float A2[16]; bool powok = true;
#pragma unroll
        for (int n = 0; n < 16; n++) {
            float a = -__expf(A_log[DIR * 2048 + d * 16 + n]);
            powok = powok && (fabsf(a + (float)(n + 1)) < 1e-3f);
            A2[n] = a * L2E;
        }
        float4 dtw = *(const float4*)(dt_w + DIR * 512 + d * 4);
        float dtbv = dt_b[DIR * 128 + d];
        float dsv = D_ssm[DIR * 128 + d];
        float h[16];
#pragma unroll
        for (int n = 0; n < 16; n++) h[n] = 0.f;
#define SCAN_BODY(EXP_BLOCK)                                                   \
        for (int tt = 0; tt < 48; tt++) {                                      \
            const float* xrow = &xd_s[tt * 40];                                \
            float4 dl4 = *(const float4*)xrow;                                 \
            float dl = dtbv + dtw.x*dl4.x + dtw.y*dl4.y + dtw.z*dl4.z + dtw.w*dl4.w; \
            float delta = (dl > 20.f) ? dl : log1pf(__expf(dl));               \
            int col = tt * 128 + ((((d >> 2) ^ (tt & 7)) << 2) | (d & 3));     \
            float uu = u_s[col];                                               \
            float du = delta * uu;                                             \
            float e[16];                                                       \
            EXP_BLOCK                                                          \
            float4 Bv0 = *(const float4*)(xrow + 4);                           \
            float4 Bv1 = *(const float4*)(xrow + 8);                           \
            float4 Bv2 = *(const float4*)(xrow + 12);                          \
            float4 Bv3 = *(const float4*)(xrow + 16);                          \
            float4 Cv0 = *(const float4*)(xrow + 20);                          \
            float4 Cv1 = *(const float4*)(xrow + 24);                          \
            float4 Cv2 = *(const float4*)(xrow + 28);                          \
            float4 Cv3 = *(const float4*)(xrow + 32);                          \
            float Bf[16] = {Bv0.x,Bv0.y,Bv0.z,Bv0.w, Bv1.x,Bv1.y,Bv1.z,Bv1.w,  \
                            Bv2.x,Bv2.y,Bv2.z,Bv2.w, Bv3.x,Bv3.y,Bv3.z,Bv3.w}; \
            float Cf[16] = {Cv0.x,Cv0.y,Cv0.z,Cv0.w, Cv1.x,Cv1.y,Cv1.z,Cv1.w,  \
                            Cv2.x,Cv2.y,Cv2.z,Cv2.w, Cv3.x,Cv3.y,Cv3.z,Cv3.w}; \
            float y = 0.f;                                                     \
            _Pragma("unroll")                                                  \
            for (int n = 0; n < 16; n++) {                                     \
                h[n] = e[n] * h[n] + du * Bf[n];                               \
                y += h[n] * Cf[n];                                             \
            }                                                                  \
            u_s[col] = y + uu * dsv;                                           \
        }
        if (powok) {
            SCAN_BODY({
                float p = exp2f(-delta * L2E);
                e[0] = p;
                _Pragma("unroll")
                for (int n = 1; n < 16; n++) e[n] = e[n-1] * p;
            })
        } else {
            SCAN_BODY({
                _Pragma("unroll")
                for (int n = 0; n < 16; n++) e[n] = exp2f(delta * A2[n]);
            })
        }
#undef SCAN_BODY
    }
    {
        const int d = tid;
        float wr[64];
        const float4* wrow = (const float4*)(ip + (128 + d) * 64);
#pragma unroll
        for (int q = 0; q < 16; q++) {
            float4 v = wrow[q];
            wr[4*q]=v.x; wr[4*q+1]=v.y; wr[4*q+2]=v.z; wr[4*q+3]=v.w;
        }
        for (int tt = 0; tt < 48; tt++) {
            const float4* xrow = (const float4*)&xs_s[tt * 68];
            float acc = 0.f;
#pragma unroll
            for (int q = 0; q < 16; q++) {
                float4 v = xrow[q];
                acc += v.x*wr[4*q] + v.y*wr[4*q+1] + v.z*wr[4*q+2] + v.w*wr[4*q+3];
            }
            int col = tt * 128 + ((((d >> 2) ^ (tt & 7)) << 2) | (d & 3));
            u_s[col] = u_s[col] * fast_silu(acc);
        }
    }
    __syncthreads();
    if (t < 48) {
        float zr[128];
        const float4* zrow = (const float4*)&u_s[t * 128];
#pragma unroll
        for (int g = 0; g < 32; g++) {
            float4 v = zrow[g ^ (t & 7)];
            zr[4*g]=v.x; zr[4*g+1]=v.y; zr[4*g+2]=v.z; zr[4*g+3]=v.w;
        }
        for (int cc = 0; cc < 32; cc++) {
            int c = wv * 32 + cc;
            const float4* wrow = (const float4*)(op + c * 128);
            float acc = 0.f;
#pragma unroll
            for (int q = 0; q < 32; q++) {
                float4 w4 = wrow[q];
                acc += zr[4*q]*w4.x + zr[4*q+1]*w4.y + zr[4*q+2]*w4.z + zr[4*q+3]*w4.w;
            }
            int oaddr = c * CS + base + t * TS;
            float vout = wdir * acc;
            if (!FIRST) vout += out[oaddr];
            out[oaddr] = vout;
        }
    }
}

// ------------------------------------------------------------- launch -----
extern "C" void kernel_launch(void* const* d_in, const int* in_sizes, int n_in,
                              void* d_out, int out_size, void* d_ws, size_t ws_size,
                              hipStream_t stream) {
    const float* x        = (const float*)d_in[0];
    const float* in_proj  = (const float*)d_in[1];
    const float* conv_w   = (const float*)d_in[2];
    const float* conv_b   = (const float*)d_in[3];
    const float* x_proj   = (const float*)d_in[4];
    const float* dt_w     = (const float*)d_in[5];
    const float* dt_b     = (const float*)d_in[6];
    const float* A_log    = (const float*)d_in[7];
    const float* D_ssm    = (const float*)d_in[8];
    const float* out_proj = (const float*)d_in[9];
    const float* ln_g     = (const float*)d_in[10];
    const float* ln_b     = (const float*)d_in[11];
    const float* alpha    = (const float*)d_in[12];
    float* out = (float*)d_out;
    float* ws  = (float*)d_ws;

    if (ws_size >= (size_t)WS_FLOATS * 4) {
        prep_kernel<<<288, 256, 0, stream>>>(in_proj, out_proj, ws);

        k1_lnproj<0><<<432, 256, 0, stream>>>(x, ln_g, ln_b, ws);
        k2_scan<0><<<2304, 128, 0, stream>>>(conv_w, conv_b, x_proj, dt_w, dt_b, A_log, D_ssm, ws);
        k3_outproj<0, true ><<<2304, 128, 0, stream>>>(alpha, ws, out);

        k1_lnproj<1><<<432, 256, 0, stream>>>(x, ln_g, ln_b, ws);
        k2_scan<1><<<2304, 128, 0, stream>>>(conv_w, conv_b, x_proj, dt_w, dt_b, A_log, D_ssm, ws);
        k3_outproj<1, false><<<2304, 128, 0, stream>>>(alpha, ws, out);

        k1_lnproj<2><<<432, 256, 0, stream>>>(x, ln_g, ln_b, ws);
        k2_scan<2><<<2304, 128, 0, stream>>>(conv_w, conv_b, x_proj, dt_w, dt_b, A_log, D_ssm, ws);
        k3_outproj<2, false><<<2304, 128, 0, stream>>>(alpha, ws, out);
    } else {
        dim3 grid(2304), block(128);
        mamba_dir_v1<0, true ><<<grid, block, 0, stream>>>(x, in_proj, conv_w, conv_b, x_proj,
            dt_w, dt_b, A_log, D_ssm, out_proj, ln_g, ln_b, alpha, out);
        mamba_dir_v1<1, false><<<grid, block, 0, stream>>>(x, in_proj, conv_w, conv_b, x_proj,
            dt_w, dt_b, A_log, D_ssm, out_proj, ln_g, ln_b, alpha, out);
        mamba_dir_v1<2, false><<<grid, block, 0, stream>>>(x, in_proj, conv_w, conv_b, x_proj,
            dt_w, dt_b, A_log, D_ssm, out_proj, ln_g, ln_b, alpha, out);
    }
}

// Round 4
// 1128.051 us; speedup vs baseline: 1.6321x; 1.6321x over previous
//
#include <hip/hip_runtime.h>
#include <math.h>

// TriDirectionalMamba: C=64, N=16, DI=128, K=4, DT_RANK=4, L=48, 48^3 grid, B=1.
// Pipeline per dir: K1 (LN+in_proj, 64-token tile GEMM, coalesced tb writes)
// -> K2 (conv+x_proj+scan per-seq, spill-free) -> K3 (gate+out_proj+accum).
// tb layout: [tau][256] with tau = seq*48 + pos; ch 0..127 = xin (later y),
// ch 128..255 = silu(res). Fallback to monolithic v1 if ws too small.

#define CS   110592      // channel stride in x = 48*48*48
#define L2E  1.44269504088896340736f

#define IPT_OFF  (110592 * 256)            // floats
#define OPT_OFF  (IPT_OFF + 3 * 64 * 256)
#define WS_FLOATS (OPT_OFF + 3 * 128 * 64)

__device__ __forceinline__ float fast_silu(float x) {
    return x / (1.0f + __expf(-x));
}

// ---------------------------------------------------------------- prep ----
__global__ void prep_kernel(const float* __restrict__ ip,
                            const float* __restrict__ op,
                            float* __restrict__ ws)
{
    float* ipT = ws + IPT_OFF;
    float* opT = ws + OPT_OFF;
    int i = blockIdx.x * 256 + threadIdx.x;
    if (i < 3 * 256 * 64) {
        int dir = i / 16384, r = i % 16384, j = r / 64, c = r % 64;
        ipT[dir * 16384 + c * 256 + j] = ip[i];
    } else {
        int k = i - 3 * 256 * 64;
        if (k < 3 * 64 * 128) {
            int dir = k / 8192, r = k % 8192, c = r / 128, dch = r % 128;
            opT[dir * 8192 + dch * 64 + c] = op[k];
        }
    }
}

// ----------------------------------------------------------------- K1 -----
// Block = 64 consecutive spatial tokens, 256 threads. X staged c-major in
// LDS (16KB); LN by wave 0; GEMM with thread = output channel j (weights in
// 64 VGPRs, X rows read as uniform ds_read_b128 broadcasts). Stores: lane=j
// -> each token's 256-ch row is a single coalesced 1KB store.
template<int DIR>
__global__ __launch_bounds__(256, 4)
void k1_lnproj(const float* __restrict__ x,
               const float* __restrict__ ln_g,
               const float* __restrict__ ln_b,
               float* __restrict__ ws)
{
    __shared__ float Xs[64 * 64];    // [c][tok]
    const float* ipT = ws + IPT_OFF + DIR * 16384;
    float* tb = ws;
    const int tid = threadIdx.x;
    const int p0 = blockIdx.x * 64;

    // load 64 tokens x 64 ch, coalesced 256B per wave-load
    {
        const int c0 = tid >> 6, j = tid & 63;
#pragma unroll
        for (int cc = 0; cc < 16; cc++) {
            int c = cc * 4 + c0;
            Xs[c * 64 + j] = x[c * CS + p0 + j];
        }
    }
    __syncthreads();

    // LayerNorm per token (wave 0; column reads stride-64 are 2-way = free)
    if (tid < 64) {
        float s1 = 0.f, s2 = 0.f;
#pragma unroll
        for (int c = 0; c < 64; c++) {
            float v = Xs[c * 64 + tid];
            s1 += v; s2 += v * v;
        }
        float m  = s1 * (1.f / 64.f);
        float rs = rsqrtf(s2 * (1.f / 64.f) - m * m + 1e-5f);
#pragma unroll
        for (int c = 0; c < 64; c++) {
            Xs[c * 64 + tid] = (Xs[c * 64 + tid] - m) * rs * ln_g[DIR * 64 + c]
                               + ln_b[DIR * 64 + c];
        }
    }
    __syncthreads();

    // GEMM: out[64 tok][256 ch], thread = ch j
    float wgt[64];
#pragma unroll
    for (int c = 0; c < 64; c++) wgt[c] = ipT[c * 256 + tid];

    for (int g = 0; g < 4; g++) {
        float acc[16];
#pragma unroll
        for (int i = 0; i < 16; i++) acc[i] = 0.f;
#pragma unroll 8
        for (int c = 0; c < 64; c++) {
            const float4* xr = (const float4*)&Xs[c * 64 + g * 16];
            float4 x0 = xr[0], x1 = xr[1], x2 = xr[2], x3 = xr[3];
            float wv = wgt[c];
            acc[0]  += x0.x * wv; acc[1]  += x0.y * wv;
            acc[2]  += x0.z * wv; acc[3]  += x0.w * wv;
            acc[4]  += x1.x * wv; acc[5]  += x1.y * wv;
            acc[6]  += x1.z * wv; acc[7]  += x1.w * wv;
            acc[8]  += x2.x * wv; acc[9]  += x2.y * wv;
            acc[10] += x2.z * wv; acc[11] += x2.w * wv;
            acc[12] += x3.x * wv; acc[13] += x3.y * wv;
            acc[14] += x3.z * wv; acc[15] += x3.w * wv;
        }
        if (tid >= 128) {    // res half -> store silu(res)
#pragma unroll
            for (int i = 0; i < 16; i++) acc[i] = fast_silu(acc[i]);
        }
#pragma unroll
        for (int i = 0; i < 16; i++) {
            int p = p0 + g * 16 + i;                  // uniform per store
            int d_sp = p / 2304, rem = p % 2304;
            int h = rem / 48, w = rem % 48;
            int tau;
            if (DIR == 0)      tau = rem * 48 + d_sp;
            else if (DIR == 1) tau = (d_sp * 48 + w) * 48 + h;
            else               tau = (d_sp * 48 + h) * 48 + w;
            tb[tau * 256 + tid] = acc[i];
        }
    }
}

// ----------------------------------------------------------------- K2 -----
// One block = one sequence (128 thr). conv+silu -> x_proj (chunked, no big
// register arrays) -> scan (direct LDS reads per step, spill-free).
// y+u*D written UNGATED over the xin slot; gating deferred to K3.
template<int DIR>
__global__ __launch_bounds__(128, 2)
void k2_scan(const float* __restrict__ conv_w,
             const float* __restrict__ conv_b,
             const float* __restrict__ x_proj,
             const float* __restrict__ dt_w,
             const float* __restrict__ dt_b,
             const float* __restrict__ A_log,
             const float* __restrict__ D_ssm,
             float* __restrict__ ws)
{
    __shared__ float u_s[48 * 132];   // rows 528B, col reads 2-way free
    __shared__ float xd_s[48 * 44];   // [0:4)=dlt [4:20)=B [20:36)=C, pad 44
    float* tb = ws;
    const int tid = threadIdx.x;
    const int t0 = blockIdx.x * (48 * 256);

    // --- phase A: depthwise causal conv + silu (thread = d) ---
    {
        const int d = tid;
        float xin[48];
#pragma unroll
        for (int t = 0; t < 48; t++) xin[t] = tb[t0 + t * 256 + d];
        float4 cw = *(const float4*)(conv_w + DIR * 512 + d * 4);
        float cb  = conv_b[DIR * 128 + d];
#pragma unroll
        for (int t = 0; t < 48; t++) {
            float a0 = (t >= 3) ? xin[t-3] : 0.f;
            float a1 = (t >= 2) ? xin[t-2] : 0.f;
            float a2 = (t >= 1) ? xin[t-1] : 0.f;
            float v = cw.x * a0 + cw.y * a1 + cw.z * a2 + cw.w * xin[t] + cb;
            u_s[t * 132 + d] = fast_silu(v);
        }
    }
    __syncthreads();

    // --- phase B: x_proj u(128) -> x_dbl(36) (lane = t, j split by wave) ---
    {
        const int t = tid & 63;
        const int wv = __builtin_amdgcn_readfirstlane(tid >> 6);
        if (t < 48) {
            float acc[18];
#pragma unroll
            for (int j = 0; j < 18; j++) acc[j] = 0.f;
            const float* xpw = x_proj + DIR * 36 * 128 + (wv * 18) * 128;
#pragma unroll
            for (int qc = 0; qc < 4; qc++) {
                float4 u4[8];
                const float4* urow = (const float4*)&u_s[t * 132 + qc * 32];
#pragma unroll
                for (int q = 0; q < 8; q++) u4[q] = urow[q];
#pragma unroll
                for (int j = 0; j < 18; j++) {
                    const float4* wr = (const float4*)(xpw + j * 128 + qc * 32);
                    float a0 = 0.f, a1 = 0.f, a2 = 0.f, a3 = 0.f;
#pragma unroll
                    for (int q = 0; q < 8; q++) {
                        float4 w4 = wr[q];
                        a0 += u4[q].x * w4.x; a1 += u4[q].y * w4.y;
                        a2 += u4[q].z * w4.z; a3 += u4[q].w * w4.w;
                    }
                    acc[j] += (a0 + a1) + (a2 + a3);
                }
            }
#pragma unroll
            for (int j = 0; j < 18; j++) xd_s[t * 44 + wv * 18 + j] = acc[j];
        }
    }
    __syncthreads();

    // --- phase C: selective scan (thread = d); xd rows read as uniform
    //     broadcasts, u column reads 2-way free, y written coalesced ---
    {
        const int d = tid;
        float A2[16]; bool powok = true;
#pragma unroll
        for (int n = 0; n < 16; n++) {
            float a = -__expf(A_log[DIR * 2048 + d * 16 + n]);
            powok = powok && (fabsf(a + (float)(n + 1)) < 1e-3f);
            A2[n] = a * L2E;
        }
        float4 dtw = *(const float4*)(dt_w + DIR * 512 + d * 4);
        float dtbv = dt_b[DIR * 128 + d];
        float dsv  = D_ssm[DIR * 128 + d];
        float h[16];
#pragma unroll
        for (int n = 0; n < 16; n++) h[n] = 0.f;

#define HN(n, Bc, Cc) h[n] = e[n] * h[n] + du * (Bc); y += h[n] * (Cc);
#define SCAN_BODY(EXP_BLOCK)                                                   \
        for (int tt = 0; tt < 48; tt++) {                                      \
            const float4* xr4 = (const float4*)&xd_s[tt * 44];                 \
            float4 dv = xr4[0];                                                \
            float uu = u_s[tt * 132 + d];                                      \
            float dl = dtbv + dtw.x*dv.x + dtw.y*dv.y + dtw.z*dv.z + dtw.w*dv.w; \
            float delta = (dl > 20.f) ? dl : log1pf(__expf(dl));               \
            float du = delta * uu;                                             \
            float e[16];                                                       \
            EXP_BLOCK                                                          \
            float4 B0 = xr4[1], B1 = xr4[2], B2 = xr4[3], B3 = xr4[4];         \
            float4 C0 = xr4[5], C1 = xr4[6], C2 = xr4[7], C3 = xr4[8];         \
            float y = 0.f;                                                     \
            HN(0,  B0.x, C0.x) HN(1,  B0.y, C0.y)                              \
            HN(2,  B0.z, C0.z) HN(3,  B0.w, C0.w)                              \
            HN(4,  B1.x, C1.x) HN(5,  B1.y, C1.y)                              \
            HN(6,  B1.z, C1.z) HN(7,  B1.w, C1.w)                              \
            HN(8,  B2.x, C2.x) HN(9,  B2.y, C2.y)                              \
            HN(10, B2.z, C2.z) HN(11, B2.w, C2.w)                              \
            HN(12, B3.x, C3.x) HN(13, B3.y, C3.y)                              \
            HN(14, B3.z, C3.z) HN(15, B3.w, C3.w)                              \
            tb[t0 + tt * 256 + d] = y + uu * dsv;                              \
        }

        if (powok) {
            SCAN_BODY({
                float p = exp2f(-delta * L2E);
                e[0] = p;
                _Pragma("unroll")
                for (int n = 1; n < 16; n++) e[n] = e[n-1] * p;
            })
        } else {
            SCAN_BODY({
                _Pragma("unroll")
                for (int n = 0; n < 16; n++) e[n] = exp2f(delta * A2[n]);
            })
        }
#undef SCAN_BODY
#undef HN
    }
}

// ----------------------------------------------------------------- K3 -----
// One block = one (d_sp, h): gates z*silu(res) while staging, out_proj via
// transposed weights, LDS transpose -> coalesced RMW into out.
template<int DIR, bool FIRST>
__global__ __launch_bounds__(128, 4)
void k3_outproj(const float* __restrict__ alpha,
                float* __restrict__ ws,
                float* __restrict__ out)
{
    __shared__ float sb[48 * 132];   // zt[48][132]; reused as outT[64][49]
    float* tb = ws;
    const float* opT = ws + OPT_OFF + DIR * 8192;
    const int tid = threadIdx.x;
    const int b = blockIdx.x;
    const int d_sp = b / 48;
    const int h = b - d_sp * 48;

    float a0 = alpha[0], a1 = alpha[1], a2 = alpha[2];
    float mx = fmaxf(a0, fmaxf(a1, a2));
    float e0 = __expf(a0 - mx), e1 = __expf(a1 - mx), e2 = __expf(a2 - mx);
    float wdir = ((DIR == 0) ? e0 : (DIR == 1) ? e1 : e2) / (e0 + e1 + e2);

#pragma unroll 4
    for (int w = 0; w < 48; w++) {
        int tau;
        if (DIR == 0)      tau = (h * 48 + w) * 48 + d_sp;
        else if (DIR == 1) tau = (d_sp * 48 + w) * 48 + h;
        else               tau = (d_sp * 48 + h) * 48 + w;
        float zv = tb[tau * 256 + tid];
        float rv = tb[tau * 256 + 128 + tid];
        sb[w * 132 + tid] = zv * rv;   // gate: z * silu(res)
    }
    __syncthreads();

    const int cp = tid & 31;
    const int wg = tid >> 5;
    float acc0[12], acc1[12];
#pragma unroll
    for (int i = 0; i < 12; i++) { acc0[i] = 0.f; acc1[i] = 0.f; }
#pragma unroll 2
    for (int dc = 0; dc < 32; dc++) {
        float w0[4], w1[4];
#pragma unroll
        for (int i = 0; i < 4; i++) {
            w0[i] = opT[(dc * 4 + i) * 64 + cp];
            w1[i] = opT[(dc * 4 + i) * 64 + cp + 32];
        }
#pragma unroll
        for (int i = 0; i < 12; i++) {
            int w = wg * 12 + i;
            float4 z4 = *(const float4*)&sb[w * 132 + dc * 4];
            acc0[i] += z4.x * w0[0] + z4.y * w0[1] + z4.z * w0[2] + z4.w * w0[3];
            acc1[i] += z4.x * w1[0] + z4.y * w1[1] + z4.z * w1[2] + z4.w * w1[3];
        }
    }
    __syncthreads();
#pragma unroll
    for (int i = 0; i < 12; i++) {
        int w = wg * 12 + i;
        sb[cp * 49 + w]        = acc0[i];
        sb[(cp + 32) * 49 + w] = acc1[i];
    }
    __syncthreads();
    const int obase = d_sp * 2304 + h * 48;
    for (int o = tid; o < 3072; o += 128) {
        int c = o / 48, w = o - c * 48;
        int addr = c * CS + obase + w;
        float val = wdir * sb[c * 49 + w];
        if (!FIRST) val += out[addr];
        out[addr] = val;
    }
}

// =================== fallback v1 (round-1, known-good) =====================
template<int DIR, bool FIRST>
__global__ __launch_bounds__(128, 2)
void mamba_dir_v1(const float* __restrict__ x, const float* __restrict__ in_proj,
                  const float* __restrict__ conv_w, const float* __restrict__ conv_b,
                  const float* __restrict__ x_proj, const float* __restrict__ dt_w,
                  const float* __restrict__ dt_b, const float* __restrict__ A_log,
                  const float* __restrict__ D_ssm, const float* __restrict__ out_proj,
                  const float* __restrict__ ln_g, const float* __restrict__ ln_b,
                  const float* __restrict__ alpha, float* __restrict__ out)
{
    __shared__ float xs_s[48 * 68];
    __shared__ float u_s[48 * 128];
    __shared__ float xd_s[48 * 40];
    const int tid = threadIdx.x;
    const int lane = tid & 63;
    const int wv = __builtin_amdgcn_readfirstlane(tid >> 6);
    const int s = blockIdx.x;
    int base, TS;
    if (DIR == 0)      { base = s;                               TS = 2304; }
    else if (DIR == 1) { base = (s / 48) * 2304 + (s % 48);      TS = 48;   }
    else               { base = (s / 48) * 2304 + (s % 48) * 48; TS = 1;    }
    const float* ip = in_proj + DIR * 256 * 64;
    const float* xp = x_proj + DIR * 36 * 128;
    const float* op = out_proj + DIR * 64 * 128;
    float a0 = alpha[0], a1 = alpha[1], a2 = alpha[2];
    float mx = fmaxf(a0, fmaxf(a1, a2));
    float e0 = __expf(a0 - mx), e1 = __expf(a1 - mx), e2 = __expf(a2 - mx);
    float wdir = ((DIR == 0) ? e0 : (DIR == 1) ? e1 : e2) / (e0 + e1 + e2);
    for (int o = tid; o < 48 * 64; o += 128) {
        int t = o % 48, c = o / 48;
        xs_s[t * 68 + c] = x[c * CS + base + t * TS];
    }
    __syncthreads();
    const int t = lane;
    float xr[64];
    if (t < 48) {
        const float4* row = (const float4*)&xs_s[t * 68];
#pragma unroll
        for (int q = 0; q < 16; q++) {
            float4 v = row[q];
            xr[4*q+0]=v.x; xr[4*q+1]=v.y; xr[4*q+2]=v.z; xr[4*q+3]=v.w;
        }
        float m = 0.f;
#pragma unroll
        for (int c = 0; c < 64; c++) m += xr[c];
        m *= (1.0f / 64.0f);
        float var = 0.f;
#pragma unroll
        for (int c = 0; c < 64; c++) { float d0 = xr[c] - m; var += d0 * d0; }
        var *= (1.0f / 64.0f);
        float rs = rsqrtf(var + 1e-5f);
#pragma unroll
        for (int c = 0; c < 64; c++)
            xr[c] = (xr[c] - m) * rs * ln_g[DIR * 64 + c] + ln_b[DIR * 64 + c];
    }
    __syncthreads();
    if (t < 48 && wv == 0) {
        float4* row = (float4*)&xs_s[t * 68];
#pragma unroll
        for (int q = 0; q < 16; q++) {
            float4 v; v.x=xr[4*q+0]; v.y=xr[4*q+1]; v.z=xr[4*q+2]; v.w=xr[4*q+3];
            row[q] = v;
        }
    }
    if (t < 48) {
        for (int jj = 0; jj < 64; jj++) {
            int j = wv * 64 + jj;
            const float4* wrow = (const float4*)(ip + j * 64);
            float acc = 0.f;
#pragma unroll
            for (int q = 0; q < 16; q++) {
                float4 w4 = wrow[q];
                acc += xr[4*q+0]*w4.x + xr[4*q+1]*w4.y + xr[4*q+2]*w4.z + xr[4*q+3]*w4.w;
            }
            int col = (((j >> 2) ^ (t & 7)) << 2) | (j & 3);
            u_s[t * 128 + col] = acc;
        }
    }
    __syncthreads();
    {
        const int d = tid;
        float4 cw = *(const float4*)(conv_w + DIR * 512 + d * 4);
        float cb = conv_b[DIR * 128 + d];
        float w0 = 0.f, w1 = 0.f, w2 = 0.f;
        for (int tt = 0; tt < 48; tt++) {
            int col = tt * 128 + ((((d >> 2) ^ (tt & 7)) << 2) | (d & 3));
            float w3 = u_s[col];
            float xc = cw.x*w0 + cw.y*w1 + cw.z*w2 + cw.w*w3 + cb;
            u_s[col] = fast_silu(xc);
            w0 = w1; w1 = w2; w2 = w3;
        }
    }
    __syncthreads();
    if (t < 48) {
        float ur[128];
        const float4* urow = (const float4*)&u_s[t * 128];
#pragma unroll
        for (int g = 0; g < 32; g++) {
            float4 v = urow[g ^ (t & 7)];
            ur[4*g]=v.x; ur[4*g+1]=v.y; ur[4*g+2]=v.z; ur[4*g+3]=v.w;
        }
        for (int jj = 0; jj < 18; jj++) {
            int j = wv * 18 + jj;
            const float4* wrow = (const float4*)(xp + j * 128);
            float acc = 0.f;
#pragma unroll
            for (int q = 0; q < 32; q++) {
                float4 w4 = wrow[q];
                acc += ur[4*q]*w4.x + ur[4*q+1]*w4.y + ur[4*q+2]*w4.z + ur[4*q+3]*w4.w;
            }
            xd_s[t * 40 + j] = acc;
        }
    }
    __syncthreads();
    {
        const int d = tid;
        float A2[16]; bool powok = true;
#pragma unroll
        for (int n = 0; n < 16; n++) {
            float a = -__expf(A_log[DIR * 2048 + d * 16 + n]);
            powok = powok && (fabsf(a + (float)(n + 1)) < 1e-3f);
            A2[n] = a * L2E;
        }
        float4 dtw = *(const float4*)(dt_w + DIR * 512 + d * 4);
        float dtbv = dt_b[DIR * 128 + d];
        float dsv = D_ssm[DIR * 128 + d];
        float h[16];
#pragma unroll
        for (int n = 0; n < 16; n++) h[n] = 0.f;
#define SCAN_BODY(EXP_BLOCK)                                                   \
        for (int tt = 0; tt < 48; tt++) {                                      \
            const float* xrow = &xd_s[tt * 40];                                \
            float4 dl4 = *(const float4*)xrow;                                 \
            float dl = dtbv + dtw.x*dl4.x + dtw.y*dl4.y + dtw.z*dl4.z + dtw.w*dl4.w; \
            float delta = (dl > 20.f) ? dl : log1pf(__expf(dl));               \
            int col = tt * 128 + ((((d >> 2) ^ (tt & 7)) << 2) | (d & 3));     \
            float uu = u_s[col];                                               \
            float du = delta * uu;                                             \
            float e[16];                                                       \
            EXP_BLOCK                                                          \
            float4 Bv0 = *(const float4*)(xrow + 4);                           \
            float4 Bv1 = *(const float4*)(xrow + 8);                           \
            float4 Bv2 = *(const float4*)(xrow + 12);                          \
            float4 Bv3 = *(const float4*)(xrow + 16);                          \
            float4 Cv0 = *(const float4*)(xrow + 20);                          \
            float4 Cv1 = *(const float4*)(xrow + 24);                          \
            float4 Cv2 = *(const float4*)(xrow + 28);                          \
            float4 Cv3 = *(const float4*)(xrow + 32);                          \
            float Bf[16] = {Bv0.x,Bv0.y,Bv0.z,Bv0.w, Bv1.x,Bv1.y,Bv1.z,Bv1.w,  \
                            Bv2.x,Bv2.y,Bv2.z,Bv2.w, Bv3.x,Bv3.y,Bv3.z,Bv3.w}; \
            float Cf[16] = {Cv0.x,Cv0.y,Cv0.z,Cv0.w, Cv1.x,Cv1.y,Cv1.z,Cv1.w,  \
                            Cv2.x,Cv2.y,Cv2.z,Cv2.w, Cv3.x,Cv3.y,Cv3.z,Cv3.w}; \
            float y = 0.f;                                                     \
            _Pragma("unroll")                                                  \
            for (int n = 0; n < 16; n++) {                                     \
                h[n] = e[n] * h[n] + du * Bf[n];                               \
                y += h[n] * Cf[n];                                             \
            }                                                                  \
            u_s[col] = y + uu * dsv;                                           \
        }
        if (powok) {
            SCAN_BODY({
                float p = exp2f(-delta * L2E);
                e[0] = p;
                _Pragma("unroll")
                for (int n = 1; n < 16; n++) e[n] = e[n-1] * p;
            })
        } else {
            SCAN_BODY({
                _Pragma("unroll")
                for (int n = 0; n < 16; n++) e[n] = exp2f(delta * A2[n]);
            })
        }
#undef SCAN_BODY
    }
    {
        const int d = tid;
        float wr[64];
        const float4* wrow = (const float4*)(ip + (128 + d) * 64);
#pragma unroll
        for (int q = 0; q < 16; q++) {
            float4 v = wrow[q];
            wr[4*q]=v.x; wr[4*q+1]=v.y; wr[4*q+2]=v.z; wr[4*q+3]=v.w;
        }
        for (int tt = 0; tt < 48; tt++) {
            const float4* xrow = (const float4*)&xs_s[tt * 68];
            float acc = 0.f;
#pragma unroll
            for (int q = 0; q < 16; q++) {
                float4 v = xrow[q];
                acc += v.x*wr[4*q] + v.y*wr[4*q+1] + v.z*wr[4*q+2] + v.w*wr[4*q+3];
            }
            int col = tt * 128 + ((((d >> 2) ^ (tt & 7)) << 2) | (d & 3));
            u_s[col] = u_s[col] * fast_silu(acc);
        }
    }
    __syncthreads();
    if (t < 48) {
        float zr[128];
        const float4* zrow = (const float4*)&u_s[t * 128];
#pragma unroll
        for (int g = 0; g < 32; g++) {
            float4 v = zrow[g ^ (t & 7)];
            zr[4*g]=v.x; zr[4*g+1]=v.y; zr[4*g+2]=v.z; zr[4*g+3]=v.w;
        }
        for (int cc = 0; cc < 32; cc++) {
            int c = wv * 32 + cc;
            const float4* wrow = (const float4*)(op + c * 128);
            float acc = 0.f;
#pragma unroll
            for (int q = 0; q < 32; q++) {
                float4 w4 = wrow[q];
                acc += zr[4*q]*w4.x + zr[4*q+1]*w4.y + zr[4*q+2]*w4.z + zr[4*q+3]*w4.w;
            }
            int oaddr = c * CS + base + t * TS;
            float vout = wdir * acc;
            if (!FIRST) vout += out[oaddr];
            out[oaddr] = vout;
        }
    }
}

// ------------------------------------------------------------- launch -----
extern "C" void kernel_launch(void* const* d_in, const int* in_sizes, int n_in,
                              void* d_out, int out_size, void* d_ws, size_t ws_size,
                              hipStream_t stream) {
    const float* x        = (const float*)d_in[0];
    const float* in_proj  = (const float*)d_in[1];
    const float* conv_w   = (const float*)d_in[2];
    const float* conv_b   = (const float*)d_in[3];
    const float* x_proj   = (const float*)d_in[4];
    const float* dt_w     = (const float*)d_in[5];
    const float* dt_b     = (const float*)d_in[6];
    const float* A_log    = (const float*)d_in[7];
    const float* D_ssm    = (const float*)d_in[8];
    const float* out_proj = (const float*)d_in[9];
    const float* ln_g     = (const float*)d_in[10];
    const float* ln_b     = (const float*)d_in[11];
    const float* alpha    = (const float*)d_in[12];
    float* out = (float*)d_out;
    float* ws  = (float*)d_ws;

    if (ws_size >= (size_t)WS_FLOATS * 4) {
        prep_kernel<<<288, 256, 0, stream>>>(in_proj, out_proj, ws);

        k1_lnproj<0><<<1728, 256, 0, stream>>>(x, ln_g, ln_b, ws);
        k2_scan<0><<<2304, 128, 0, stream>>>(conv_w, conv_b, x_proj, dt_w, dt_b, A_log, D_ssm, ws);
        k3_outproj<0, true ><<<2304, 128, 0, stream>>>(alpha, ws, out);

        k1_lnproj<1><<<1728, 256, 0, stream>>>(x, ln_g, ln_b, ws);
        k2_scan<1><<<2304, 128, 0, stream>>>(conv_w, conv_b, x_proj, dt_w, dt_b, A_log, D_ssm, ws);
        k3_outproj<1, false><<<2304, 128, 0, stream>>>(alpha, ws, out);

        k1_lnproj<2><<<1728, 256, 0, stream>>>(x, ln_g, ln_b, ws);
        k2_scan<2><<<2304, 128, 0, stream>>>(conv_w, conv_b, x_proj, dt_w, dt_b, A_log, D_ssm, ws);
        k3_outproj<2, false><<<2304, 128, 0, stream>>>(alpha, ws, out);
    } else {
        dim3 grid(2304), block(128);
        mamba_dir_v1<0, true ><<<grid, block, 0, stream>>>(x, in_proj, conv_w, conv_b, x_proj,
            dt_w, dt_b, A_log, D_ssm, out_proj, ln_g, ln_b, alpha, out);
        mamba_dir_v1<1, false><<<grid, block, 0, stream>>>(x, in_proj, conv_w, conv_b, x_proj,
            dt_w, dt_b, A_log, D_ssm, out_proj, ln_g, ln_b, alpha, out);
        mamba_dir_v1<2, false><<<grid, block, 0, stream>>>(x, in_proj, conv_w, conv_b, x_proj,
            dt_w, dt_b, A_log, D_ssm, out_proj, ln_g, ln_b, alpha, out);
    }
}